// Round 4
// baseline (236.296 us; speedup 1.0000x reference)
//
#include <hip/hip_runtime.h>
#include <math.h>

// CriticGraphPolicy fused kernel, MI355X (gfx950). Round 4.
// Dead code removed: m_up=0, m_td=0, msg-MLP unused.
// R4 = R3 with the staging bug fixed: stage_tile now covers ALL granules
// (R3 skipped bytes 8K..16K -> garbage). Uniform 3 vmem ops/wave/tile makes
// the counted end-of-iter wait vmcnt(3). Epilogue barriers -> __syncthreads()
// (xred aliases h1t; full fence removes the reordering hazard).

#define TBROWS 128
#define NTHR   512
#define BTOT   65536
#define NBLK   (BTOT / TBROWS)
#define TILE_B 23808            // bytes per packed weight tile (w2 19200 + w1 4608)
#define TILE_U 11904            // u16 per tile
#define W2_B   19200
#define NTILE  26               // 2 q-nets x 13 k-tiles

typedef float  f32x4 __attribute__((ext_vector_type(4)));
typedef __bf16 bf16x8 __attribute__((ext_vector_type(8)));
typedef unsigned short u16x8 __attribute__((ext_vector_type(8)));

struct Params {
  const float* state; const float* action;
  const float* f1w; const float* f1b;
  const float* f2w; const float* f2b;
  const float* f3w; const float* f3b;
  const float* qp[12];          // q1: w1,b1,w2,b2,w3,b3 ; q2: same
  const unsigned char* img;     // packed bf16 weight images (d_ws)
  float* out;
};

struct PackP {
  const float* qp[12];
  unsigned short* ws;
};

__device__ __forceinline__ unsigned short f2b(float f) {
  union { float f; unsigned int u; } v; v.f = f;
  return (unsigned short)((v.u + 0x7fffu + ((v.u >> 16) & 1u)) >> 16);
}
__device__ __forceinline__ float b2f(unsigned short u) {
  union { unsigned int u; float f; } v; v.u = ((unsigned int)u) << 16;
  return v.f;
}
__device__ __forceinline__ f32x4 MFMA(bf16x8 a, bf16x8 b, f32x4 c) {
  return __builtin_amdgcn_mfma_f32_16x16x32_bf16(a, b, c, 0, 0, 0);
}
__device__ __forceinline__ bf16x8 lds8(const unsigned short* p) {
  return __builtin_bit_cast(bf16x8, *(const u16x8*)p);
}
__device__ __forceinline__ void gl_lds16(const void* g, void* l) {
  __builtin_amdgcn_global_load_lds(
      (__attribute__((address_space(1))) void*)(unsigned long long)(const char*)g,
      (__attribute__((address_space(3))) void*)(unsigned long long)(char*)l,
      16, 0, 0);
}
__device__ __forceinline__ void gl_lds4(const void* g, void* l) {
  __builtin_amdgcn_global_load_lds(
      (__attribute__((address_space(1))) void*)(unsigned long long)(const char*)g,
      (__attribute__((address_space(3))) void*)(unsigned long long)(char*)l,
      4, 0, 0);
}
__device__ __forceinline__ float ftanh(float x) {
  // tanh(x) = (e^2x - 1)/(e^2x + 1); e^2x = 2^(x*2/ln2). Inputs bounded (<~4).
  float e = __builtin_amdgcn_exp2f(x * 2.885390081777927f);
  return (e - 1.0f) * __builtin_amdgcn_rcpf(e + 1.0f);
}

// stage one 23808-B tile. Granules of 1 KB (64 lanes x 16 B):
//   wave w (0..7): granules w and 8+w; waves 0..6: granule 16+w;
//   wave 7: 256-B tail at 23552 (64 lanes x 4 B).
// Exactly 3 vmem ops per wave. LDS dst is wave-uniform base (HW adds
// lane*width); global src is per-lane.
__device__ __forceinline__ void stage_tile(const unsigned char* img, int tile,
                                           unsigned char* dst, int w, int lane) {
  const unsigned char* src = img + (size_t)tile * TILE_B;
  gl_lds16(src + (w << 10) + lane * 16,       dst + (w << 10));
  gl_lds16(src + ((8 + w) << 10) + lane * 16, dst + ((8 + w) << 10));
  if (w < 7)  gl_lds16(src + ((16 + w) << 10) + lane * 16, dst + ((16 + w) << 10));
  else        gl_lds4 (src + 23552 + lane * 4,             dst + 23552);
}

// ---------------- weight pack kernel ----------------
// image tile (q,kt) at (q*13+kt)*23808 bytes:
//   [0..19200):    w2 as [kc 4][col 300][koff 8] bf16 (kg=kt*32+kc*8+koff; zero if kg>=400)
//   [19200..23808): w1eff as [col 32][k 72] bf16 (k<39: w1[6+k][cg], k==39: b1[cg], else 0)
__global__ void pack_weights(PackP P) {
  const int b = blockIdx.x, tid = threadIdx.x;
  if (b < 61) {                       // w2: 26 tiles * 4 kc * 300 col = 31200 vec8 stores
    int idx = b * 512 + tid;
    if (idx >= 31200) return;
    int col = idx % 300; int r = idx / 300;
    int kc = r & 3, tile = r >> 2;
    int q = tile / 13, kt = tile % 13;
    const float* w2 = P.qp[q * 6 + 2];
    unsigned short vals[8];
    #pragma unroll
    for (int koff = 0; koff < 8; ++koff) {
      int kg = kt * 32 + kc * 8 + koff;
      float v = (kg < 400) ? w2[kg * 300 + col] : 0.f;
      vals[koff] = f2b(v);
    }
    *(u16x8*)(P.ws + (size_t)tile * TILE_U + (size_t)(kc * 300 + col) * 8) = *(const u16x8*)vals;
  } else {                            // w1: 26 tiles * 2304 u16 = 59904
    int idx = (b - 61) * 512 + tid;
    if (idx >= 59904) return;
    int e = idx % 2304, tile = idx / 2304;
    int q = tile / 13, kt = tile % 13;
    int col = e / 72, k = e % 72;
    int cg = kt * 32 + col;
    unsigned short v = 0;
    if (cg < 400) {
      if (k < 39) v = f2b(P.qp[q * 6 + 0][(6 + k) * 400 + cg]);
      else if (k == 39) v = f2b(P.qp[q * 6 + 1][cg]);
    }
    P.ws[(size_t)tile * TILE_U + 9600 + e] = v;
  }
}

// ---------------- main fused kernel ----------------
__global__ __launch_bounds__(NTHR, 4) void critic_fused_kernel(Params P) {
  // LDS map (80640 B, 2 blocks/CU):
  //  [0..23808)       buf0
  //  [23808..47616)   buf1
  //  [47616..71424)   buf2; aliased: phase0 hp / xumA [128][72] u16 (18432 B)
  //  [71424..80640)   h1t [128][36] u16 (9216 B); xred [128][4] f32 aliases start
  __shared__ __align__(16) unsigned char smem[80640];
  unsigned char* bufs = smem;
  unsigned short* xumA = (unsigned short*)(smem + 2 * TILE_B);
  unsigned short* h1t  = (unsigned short*)(smem + 3 * TILE_B);
  float*          xred = (float*)(smem + 3 * TILE_B);

  const int tid  = threadIdx.x;
  const int lane = tid & 63, w = tid >> 6;
  const int rl = lane & 15, g = lane >> 4;
  const int row = tid >> 2, sub = tid & 3;
  const long grow = (long)blockIdx.x * TBROWS + row;

  // prefetch tiles 0,1 into buf0,buf1 (overlaps phase 0)
  stage_tile(P.img, 0, bufs, w, lane);
  stage_tile(P.img, 1, bufs + TILE_B, w, lane);

  // ---------------- phase 0: feature MLP (f32 VALU) ----------------
  float sa[33];
  {
    const float4* sp = (const float4*)(P.state + grow * 32);
    #pragma unroll
    for (int c = 0; c < 8; ++c) {
      float4 v = sp[c];
      sa[c*4+0] = v.x; sa[c*4+1] = v.y; sa[c*4+2] = v.z; sa[c*4+3] = v.w;
    }
    sa[32] = P.action[grow];
  }
  const int j0 = sub * 16;
  float acc[16];
  // fc1: h = tanh(l2norm(sa @ w1 + b1))
  #pragma unroll
  for (int j = 0; j < 16; ++j) acc[j] = P.f1b[j0 + j];
  #pragma unroll
  for (int i = 0; i < 33; ++i) {
    const float s = sa[i];
    const float4* wr = (const float4*)(P.f1w + i * 64 + j0);
    #pragma unroll
    for (int c = 0; c < 4; ++c) {
      float4 wv = wr[c];
      acc[c*4+0] += s * wv.x; acc[c*4+1] += s * wv.y;
      acc[c*4+2] += s * wv.z; acc[c*4+3] += s * wv.w;
    }
  }
  {
    float ss = 0.f;
    #pragma unroll
    for (int j = 0; j < 16; ++j) ss += acc[j] * acc[j];
    ss += __shfl_xor(ss, 1, 64); ss += __shfl_xor(ss, 2, 64);
    const float sc = 1.f / fmaxf(sqrtf(ss), 1e-12f);
    #pragma unroll
    for (int j = 0; j < 16; ++j) xumA[row * 72 + j0 + j] = f2b(ftanh(acc[j] * sc));
  }
  __syncthreads();
  // fc2: h2 = tanh(h @ w2[0:64] + b2)
  #pragma unroll
  for (int j = 0; j < 16; ++j) acc[j] = P.f2b[j0 + j];
  for (int i = 0; i < 64; ++i) {
    const float hv = b2f(xumA[row * 72 + i]);
    const float4* wr = (const float4*)(P.f2w + i * 64 + j0);
    #pragma unroll
    for (int c = 0; c < 4; ++c) {
      float4 wv = wr[c];
      acc[c*4+0] += hv * wv.x; acc[c*4+1] += hv * wv.y;
      acc[c*4+2] += hv * wv.z; acc[c*4+3] += hv * wv.w;
    }
  }
  __syncthreads();
  #pragma unroll
  for (int j = 0; j < 16; ++j) xumA[row * 72 + j0 + j] = f2b(ftanh(acc[j]));
  __syncthreads();
  // fc3: msg_up = l2norm(h2 @ w3 + b3)
  const int j0m = sub * 8;
  float am[8];
  #pragma unroll
  for (int j = 0; j < 8; ++j) am[j] = P.f3b[j0m + j];
  for (int i = 0; i < 64; ++i) {
    const float hv = b2f(xumA[row * 72 + i]);
    const float4* wr = (const float4*)(P.f3w + i * 32 + j0m);
    #pragma unroll
    for (int c = 0; c < 2; ++c) {
      float4 wv = wr[c];
      am[c*4+0] += hv * wv.x; am[c*4+1] += hv * wv.y;
      am[c*4+2] += hv * wv.z; am[c*4+3] += hv * wv.w;
    }
  }
  float sm = 0.f;
  #pragma unroll
  for (int j = 0; j < 8; ++j) sm += am[j] * am[j];
  sm += __shfl_xor(sm, 1, 64); sm += __shfl_xor(sm, 2, 64);
  const float scm = 1.f / fmaxf(sqrtf(sm), 1e-12f);
  __syncthreads();                    // hp reads done; rebuild as xum
  // xum features (K padded to 64): f0..2=pos, f3..5=pos, f6..37=msg, f38=action, f39=1
  #pragma unroll
  for (int k = 0; k < 16; ++k) xumA[row * 72 + j0 + k] = 0;
  __syncthreads();
  if (sub == 0) {
    #pragma unroll
    for (int c = 0; c < 3; ++c) {
      unsigned short pb = f2b(sa[c]);
      xumA[row * 72 + c] = pb;
      xumA[row * 72 + 3 + c] = pb;
    }
    xumA[row * 72 + 38] = f2b(sa[32]);
    xumA[row * 72 + 39] = 0x3f80;     // 1.0
  }
  #pragma unroll
  for (int j = 0; j < 8; ++j) xumA[row * 72 + 6 + j0m + j] = f2b(am[j] * scm);
  __syncthreads();

  // layer1 A-fragments (rows 16w..16w+15), shared by both q-nets
  bf16x8 af0 = lds8(&xumA[(w * 16 + rl) * 72 + g * 8]);
  bf16x8 af1 = lds8(&xumA[(w * 16 + rl) * 72 + 32 + g * 8]);
  asm volatile("s_waitcnt vmcnt(0) lgkmcnt(0)" ::: "memory");
  __builtin_amdgcn_s_barrier();       // frags held; buf2 free; tiles 0,1 resident

  const int wm = w >> 2, wn = w & 3;  // layer2: 2 M-halves x 4 N-quarters
  f32x4 acc2[4][5];

  for (int tt = 0; tt < NTILE; ++tt) {
    const int kt = (tt < 13) ? tt : tt - 13;
    const int qx = (tt < 13) ? 0 : 1;
    unsigned char* bufc = bufs + (tt % 3) * TILE_B;
    if (kt == 0) {
      #pragma unroll
      for (int mt = 0; mt < 4; ++mt)
        #pragma unroll
        for (int jn = 0; jn < 5; ++jn) acc2[mt][jn] = (f32x4){0.f, 0.f, 0.f, 0.f};
    }
    // issue DMA for tile tt+2 (its buffer's readers finished at end of iter tt-1)
    if (tt + 2 < NTILE)
      stage_tile(P.img, tt + 2, bufs + ((tt + 2) % 3) * TILE_B, w, lane);

    // layer1: wave w -> rows 16w..16w+15, 32 cols (this tile's k-slice)
    const unsigned short* w1c = (const unsigned short*)(bufc + W2_B);
    f32x4 a1[2];
    a1[0] = (f32x4){0.f, 0.f, 0.f, 0.f};
    a1[1] = (f32x4){0.f, 0.f, 0.f, 0.f};
    #pragma unroll
    for (int nt = 0; nt < 2; ++nt) {
      a1[nt] = MFMA(af0, lds8(&w1c[(nt * 16 + rl) * 72 + g * 8]), a1[nt]);
      a1[nt] = MFMA(af1, lds8(&w1c[(nt * 16 + rl) * 72 + 32 + g * 8]), a1[nt]);
    }
    #pragma unroll
    for (int nt = 0; nt < 2; ++nt)
      #pragma unroll
      for (int i = 0; i < 4; ++i)
        h1t[(w * 16 + g * 4 + i) * 36 + nt * 16 + rl] = f2b(fmaxf(a1[nt][i], 0.f));
    asm volatile("s_waitcnt lgkmcnt(0)" ::: "memory");
    __builtin_amdgcn_s_barrier();     // h1t ready; prefetch DMAs stay in flight
    // layer2: wave (wm,wn): rows 64wm..+63 x cols 80wn..+79
    const unsigned short* w2l = (const unsigned short*)bufc;
    bf16x8 a2f[4];
    #pragma unroll
    for (int mt = 0; mt < 4; ++mt)
      a2f[mt] = lds8(&h1t[(wm * 64 + mt * 16 + rl) * 36 + g * 8]);
    #pragma unroll
    for (int jn = 0; jn < 5; ++jn) {
      bf16x8 bff = lds8(&w2l[g * 2400 + (wn * 80 + jn * 16 + rl) * 8]);
      #pragma unroll
      for (int mt = 0; mt < 4; ++mt)
        acc2[mt][jn] = MFMA(a2f[mt], bff, acc2[mt][jn]);
    }
    // epilogue after last k-tile of each q-net
    if (kt == 12) {
      __syncthreads();                // all h1t reads done; xred may alias-clobber
      const float* b2p = P.qp[qx * 6 + 3];
      const float* w3  = P.qp[qx * 6 + 4];
      const float* b3  = P.qp[qx * 6 + 5];
      float xp[4][4];
      #pragma unroll
      for (int mt = 0; mt < 4; ++mt)
        #pragma unroll
        for (int i = 0; i < 4; ++i) xp[mt][i] = 0.f;
      #pragma unroll
      for (int jn = 0; jn < 5; ++jn) {
        int n = wn * 80 + jn * 16 + rl;
        if (n < 300) {
          float bv = b2p[n], wv = w3[n];
          #pragma unroll
          for (int mt = 0; mt < 4; ++mt)
            #pragma unroll
            for (int i = 0; i < 4; ++i)
              xp[mt][i] += fmaxf(acc2[mt][jn][i] + bv, 0.f) * wv;
        }
      }
      #pragma unroll
      for (int off = 1; off < 16; off <<= 1)
        #pragma unroll
        for (int mt = 0; mt < 4; ++mt)
          #pragma unroll
          for (int i = 0; i < 4; ++i)
            xp[mt][i] += __shfl_xor(xp[mt][i], off, 64);
      if (rl == 0) {
        #pragma unroll
        for (int mt = 0; mt < 4; ++mt)
          #pragma unroll
          for (int i = 0; i < 4; ++i)
            xred[(wm * 64 + mt * 16 + g * 4 + i) * 4 + wn] = xp[mt][i];
      }
      __syncthreads();                // xred visible
      if (tid < TBROWS) {
        const float4 xv = *(const float4*)&xred[tid * 4];
        P.out[(size_t)qx * BTOT + (size_t)blockIdx.x * TBROWS + tid] =
            xv.x + xv.y + xv.z + xv.w + b3[0];
      }
    }
    // iter end: confirm tile tt+1 resident (counted wait: tile tt+2's 3 ops
    // may stay in flight; FIFO retirement => <=3 outstanding means tt+1 landed)
    if (tt < NTILE - 1) {
      if (tt == NTILE - 2) { asm volatile("s_waitcnt vmcnt(0)" ::: "memory"); }
      else                 { asm volatile("s_waitcnt vmcnt(3)" ::: "memory"); }
      __builtin_amdgcn_s_barrier();
    }
  }
}

extern "C" void kernel_launch(void* const* d_in, const int* in_sizes, int n_in,
                              void* d_out, int out_size, void* d_ws, size_t ws_size,
                              hipStream_t stream) {
  (void)in_sizes; (void)n_in; (void)out_size; (void)ws_size;
  PackP K;
  for (int i = 0; i < 12; ++i) K.qp[i] = (const float*)d_in[10 + i];
  K.ws = (unsigned short*)d_ws;
  pack_weights<<<dim3(178), dim3(512), 0, stream>>>(K);

  Params P;
  P.state  = (const float*)d_in[0];
  P.action = (const float*)d_in[1];
  P.f1w = (const float*)d_in[2]; P.f1b = (const float*)d_in[3];
  P.f2w = (const float*)d_in[4]; P.f2b = (const float*)d_in[5];
  P.f3w = (const float*)d_in[6]; P.f3b = (const float*)d_in[7];
  for (int i = 0; i < 12; ++i) P.qp[i] = (const float*)d_in[10 + i];
  P.img = (const unsigned char*)d_ws;
  P.out = (float*)d_out;
  critic_fused_kernel<<<dim3(NBLK), dim3(NTHR), 0, stream>>>(P);
}

// Round 5
// 223.473 us; speedup vs baseline: 1.0574x; 1.0574x over previous
//
#include <hip/hip_runtime.h>
#include <math.h>

// CriticGraphPolicy fused kernel, MI355X (gfx950). Round 5.
// Dead code removed: m_up=0, m_td=0, msg-MLP unused.
// R5 = R4 with ONE change: __launch_bounds__(NTHR, 2) instead of (NTHR, 4).
// R2-R4's (NTHR,4) capped the unified VGPR+AGPR budget at 128/wave; the
// 80-reg acc2 accumulator state spilled to scratch (WRITE_SIZE 137 MB,
// VGPR_Count 64) and the spill's L2 round-trips were the real serializer
// (MfmaUtil stuck at ~7%). (NTHR,2) gives a 256-reg budget -> no spill.

#define TBROWS 128
#define NTHR   512
#define BTOT   65536
#define NBLK   (BTOT / TBROWS)
#define TILE_B 23808            // bytes per packed weight tile (w2 19200 + w1 4608)
#define TILE_U 11904            // u16 per tile
#define W2_B   19200
#define NTILE  26               // 2 q-nets x 13 k-tiles

typedef float  f32x4 __attribute__((ext_vector_type(4)));
typedef __bf16 bf16x8 __attribute__((ext_vector_type(8)));
typedef unsigned short u16x8 __attribute__((ext_vector_type(8)));

struct Params {
  const float* state; const float* action;
  const float* f1w; const float* f1b;
  const float* f2w; const float* f2b;
  const float* f3w; const float* f3b;
  const float* qp[12];          // q1: w1,b1,w2,b2,w3,b3 ; q2: same
  const unsigned char* img;     // packed bf16 weight images (d_ws)
  float* out;
};

struct PackP {
  const float* qp[12];
  unsigned short* ws;
};

__device__ __forceinline__ unsigned short f2b(float f) {
  union { float f; unsigned int u; } v; v.f = f;
  return (unsigned short)((v.u + 0x7fffu + ((v.u >> 16) & 1u)) >> 16);
}
__device__ __forceinline__ float b2f(unsigned short u) {
  union { unsigned int u; float f; } v; v.u = ((unsigned int)u) << 16;
  return v.f;
}
__device__ __forceinline__ f32x4 MFMA(bf16x8 a, bf16x8 b, f32x4 c) {
  return __builtin_amdgcn_mfma_f32_16x16x32_bf16(a, b, c, 0, 0, 0);
}
__device__ __forceinline__ bf16x8 lds8(const unsigned short* p) {
  return __builtin_bit_cast(bf16x8, *(const u16x8*)p);
}
__device__ __forceinline__ void gl_lds16(const void* g, void* l) {
  __builtin_amdgcn_global_load_lds(
      (__attribute__((address_space(1))) void*)(unsigned long long)(const char*)g,
      (__attribute__((address_space(3))) void*)(unsigned long long)(char*)l,
      16, 0, 0);
}
__device__ __forceinline__ void gl_lds4(const void* g, void* l) {
  __builtin_amdgcn_global_load_lds(
      (__attribute__((address_space(1))) void*)(unsigned long long)(const char*)g,
      (__attribute__((address_space(3))) void*)(unsigned long long)(char*)l,
      4, 0, 0);
}
__device__ __forceinline__ float ftanh(float x) {
  // tanh(x) = (e^2x - 1)/(e^2x + 1); e^2x = 2^(x*2/ln2). Inputs bounded (<~4).
  float e = __builtin_amdgcn_exp2f(x * 2.885390081777927f);
  return (e - 1.0f) * __builtin_amdgcn_rcpf(e + 1.0f);
}

// stage one 23808-B tile. Granules of 1 KB (64 lanes x 16 B):
//   wave w (0..7): granules w and 8+w; waves 0..6: granule 16+w;
//   wave 7: 256-B tail at 23552 (64 lanes x 4 B).
// Exactly 3 vmem ops per wave. LDS dst is wave-uniform base (HW adds
// lane*width); global src is per-lane.
__device__ __forceinline__ void stage_tile(const unsigned char* img, int tile,
                                           unsigned char* dst, int w, int lane) {
  const unsigned char* src = img + (size_t)tile * TILE_B;
  gl_lds16(src + (w << 10) + lane * 16,       dst + (w << 10));
  gl_lds16(src + ((8 + w) << 10) + lane * 16, dst + ((8 + w) << 10));
  if (w < 7)  gl_lds16(src + ((16 + w) << 10) + lane * 16, dst + ((16 + w) << 10));
  else        gl_lds4 (src + 23552 + lane * 4,             dst + 23552);
}

// ---------------- weight pack kernel ----------------
// image tile (q,kt) at (q*13+kt)*23808 bytes:
//   [0..19200):    w2 as [kc 4][col 300][koff 8] bf16 (kg=kt*32+kc*8+koff; zero if kg>=400)
//   [19200..23808): w1eff as [col 32][k 72] bf16 (k<39: w1[6+k][cg], k==39: b1[cg], else 0)
__global__ void pack_weights(PackP P) {
  const int b = blockIdx.x, tid = threadIdx.x;
  if (b < 61) {                       // w2: 26 tiles * 4 kc * 300 col = 31200 vec8 stores
    int idx = b * 512 + tid;
    if (idx >= 31200) return;
    int col = idx % 300; int r = idx / 300;
    int kc = r & 3, tile = r >> 2;
    int q = tile / 13, kt = tile % 13;
    const float* w2 = P.qp[q * 6 + 2];
    unsigned short vals[8];
    #pragma unroll
    for (int koff = 0; koff < 8; ++koff) {
      int kg = kt * 32 + kc * 8 + koff;
      float v = (kg < 400) ? w2[kg * 300 + col] : 0.f;
      vals[koff] = f2b(v);
    }
    *(u16x8*)(P.ws + (size_t)tile * TILE_U + (size_t)(kc * 300 + col) * 8) = *(const u16x8*)vals;
  } else {                            // w1: 26 tiles * 2304 u16 = 59904
    int idx = (b - 61) * 512 + tid;
    if (idx >= 59904) return;
    int e = idx % 2304, tile = idx / 2304;
    int q = tile / 13, kt = tile % 13;
    int col = e / 72, k = e % 72;
    int cg = kt * 32 + col;
    unsigned short v = 0;
    if (cg < 400) {
      if (k < 39) v = f2b(P.qp[q * 6 + 0][(6 + k) * 400 + cg]);
      else if (k == 39) v = f2b(P.qp[q * 6 + 1][cg]);
    }
    P.ws[(size_t)tile * TILE_U + 9600 + e] = v;
  }
}

// ---------------- main fused kernel ----------------
__global__ __launch_bounds__(NTHR, 2) void critic_fused_kernel(Params P) {
  // LDS map (80640 B):
  //  [0..23808)       buf0
  //  [23808..47616)   buf1
  //  [47616..71424)   buf2; aliased: phase0 hp / xumA [128][72] u16 (18432 B)
  //  [71424..80640)   h1t [128][36] u16 (9216 B); xred [128][4] f32 aliases start
  __shared__ __align__(16) unsigned char smem[80640];
  unsigned char* bufs = smem;
  unsigned short* xumA = (unsigned short*)(smem + 2 * TILE_B);
  unsigned short* h1t  = (unsigned short*)(smem + 3 * TILE_B);
  float*          xred = (float*)(smem + 3 * TILE_B);

  const int tid  = threadIdx.x;
  const int lane = tid & 63, w = tid >> 6;
  const int rl = lane & 15, g = lane >> 4;
  const int row = tid >> 2, sub = tid & 3;
  const long grow = (long)blockIdx.x * TBROWS + row;

  // prefetch tiles 0,1 into buf0,buf1 (overlaps phase 0)
  stage_tile(P.img, 0, bufs, w, lane);
  stage_tile(P.img, 1, bufs + TILE_B, w, lane);

  // ---------------- phase 0: feature MLP (f32 VALU) ----------------
  float sa[33];
  {
    const float4* sp = (const float4*)(P.state + grow * 32);
    #pragma unroll
    for (int c = 0; c < 8; ++c) {
      float4 v = sp[c];
      sa[c*4+0] = v.x; sa[c*4+1] = v.y; sa[c*4+2] = v.z; sa[c*4+3] = v.w;
    }
    sa[32] = P.action[grow];
  }
  const int j0 = sub * 16;
  float acc[16];
  // fc1: h = tanh(l2norm(sa @ w1 + b1))
  #pragma unroll
  for (int j = 0; j < 16; ++j) acc[j] = P.f1b[j0 + j];
  #pragma unroll
  for (int i = 0; i < 33; ++i) {
    const float s = sa[i];
    const float4* wr = (const float4*)(P.f1w + i * 64 + j0);
    #pragma unroll
    for (int c = 0; c < 4; ++c) {
      float4 wv = wr[c];
      acc[c*4+0] += s * wv.x; acc[c*4+1] += s * wv.y;
      acc[c*4+2] += s * wv.z; acc[c*4+3] += s * wv.w;
    }
  }
  {
    float ss = 0.f;
    #pragma unroll
    for (int j = 0; j < 16; ++j) ss += acc[j] * acc[j];
    ss += __shfl_xor(ss, 1, 64); ss += __shfl_xor(ss, 2, 64);
    const float sc = 1.f / fmaxf(sqrtf(ss), 1e-12f);
    #pragma unroll
    for (int j = 0; j < 16; ++j) xumA[row * 72 + j0 + j] = f2b(ftanh(acc[j] * sc));
  }
  __syncthreads();
  // fc2: h2 = tanh(h @ w2[0:64] + b2)
  #pragma unroll
  for (int j = 0; j < 16; ++j) acc[j] = P.f2b[j0 + j];
  for (int i = 0; i < 64; ++i) {
    const float hv = b2f(xumA[row * 72 + i]);
    const float4* wr = (const float4*)(P.f2w + i * 64 + j0);
    #pragma unroll
    for (int c = 0; c < 4; ++c) {
      float4 wv = wr[c];
      acc[c*4+0] += hv * wv.x; acc[c*4+1] += hv * wv.y;
      acc[c*4+2] += hv * wv.z; acc[c*4+3] += hv * wv.w;
    }
  }
  __syncthreads();
  #pragma unroll
  for (int j = 0; j < 16; ++j) xumA[row * 72 + j0 + j] = f2b(ftanh(acc[j]));
  __syncthreads();
  // fc3: msg_up = l2norm(h2 @ w3 + b3)
  const int j0m = sub * 8;
  float am[8];
  #pragma unroll
  for (int j = 0; j < 8; ++j) am[j] = P.f3b[j0m + j];
  for (int i = 0; i < 64; ++i) {
    const float hv = b2f(xumA[row * 72 + i]);
    const float4* wr = (const float4*)(P.f3w + i * 32 + j0m);
    #pragma unroll
    for (int c = 0; c < 2; ++c) {
      float4 wv = wr[c];
      am[c*4+0] += hv * wv.x; am[c*4+1] += hv * wv.y;
      am[c*4+2] += hv * wv.z; am[c*4+3] += hv * wv.w;
    }
  }
  float sm = 0.f;
  #pragma unroll
  for (int j = 0; j < 8; ++j) sm += am[j] * am[j];
  sm += __shfl_xor(sm, 1, 64); sm += __shfl_xor(sm, 2, 64);
  const float scm = 1.f / fmaxf(sqrtf(sm), 1e-12f);
  __syncthreads();                    // hp reads done; rebuild as xum
  // xum features (K padded to 64): f0..2=pos, f3..5=pos, f6..37=msg, f38=action, f39=1
  #pragma unroll
  for (int k = 0; k < 16; ++k) xumA[row * 72 + j0 + k] = 0;
  __syncthreads();
  if (sub == 0) {
    #pragma unroll
    for (int c = 0; c < 3; ++c) {
      unsigned short pb = f2b(sa[c]);
      xumA[row * 72 + c] = pb;
      xumA[row * 72 + 3 + c] = pb;
    }
    xumA[row * 72 + 38] = f2b(sa[32]);
    xumA[row * 72 + 39] = 0x3f80;     // 1.0
  }
  #pragma unroll
  for (int j = 0; j < 8; ++j) xumA[row * 72 + 6 + j0m + j] = f2b(am[j] * scm);
  __syncthreads();

  // layer1 A-fragments (rows 16w..16w+15), shared by both q-nets
  bf16x8 af0 = lds8(&xumA[(w * 16 + rl) * 72 + g * 8]);
  bf16x8 af1 = lds8(&xumA[(w * 16 + rl) * 72 + 32 + g * 8]);
  asm volatile("s_waitcnt vmcnt(0) lgkmcnt(0)" ::: "memory");
  __builtin_amdgcn_s_barrier();       // frags held; buf2 free; tiles 0,1 resident

  const int wm = w >> 2, wn = w & 3;  // layer2: 2 M-halves x 4 N-quarters
  f32x4 acc2[4][5];

  for (int tt = 0; tt < NTILE; ++tt) {
    const int kt = (tt < 13) ? tt : tt - 13;
    const int qx = (tt < 13) ? 0 : 1;
    unsigned char* bufc = bufs + (tt % 3) * TILE_B;
    if (kt == 0) {
      #pragma unroll
      for (int mt = 0; mt < 4; ++mt)
        #pragma unroll
        for (int jn = 0; jn < 5; ++jn) acc2[mt][jn] = (f32x4){0.f, 0.f, 0.f, 0.f};
    }
    // issue DMA for tile tt+2 (its buffer's readers finished at end of iter tt-1)
    if (tt + 2 < NTILE)
      stage_tile(P.img, tt + 2, bufs + ((tt + 2) % 3) * TILE_B, w, lane);

    // layer1: wave w -> rows 16w..16w+15, 32 cols (this tile's k-slice)
    const unsigned short* w1c = (const unsigned short*)(bufc + W2_B);
    f32x4 a1[2];
    a1[0] = (f32x4){0.f, 0.f, 0.f, 0.f};
    a1[1] = (f32x4){0.f, 0.f, 0.f, 0.f};
    #pragma unroll
    for (int nt = 0; nt < 2; ++nt) {
      a1[nt] = MFMA(af0, lds8(&w1c[(nt * 16 + rl) * 72 + g * 8]), a1[nt]);
      a1[nt] = MFMA(af1, lds8(&w1c[(nt * 16 + rl) * 72 + 32 + g * 8]), a1[nt]);
    }
    #pragma unroll
    for (int nt = 0; nt < 2; ++nt)
      #pragma unroll
      for (int i = 0; i < 4; ++i)
        h1t[(w * 16 + g * 4 + i) * 36 + nt * 16 + rl] = f2b(fmaxf(a1[nt][i], 0.f));
    asm volatile("s_waitcnt lgkmcnt(0)" ::: "memory");
    __builtin_amdgcn_s_barrier();     // h1t ready; prefetch DMAs stay in flight
    // layer2: wave (wm,wn): rows 64wm..+63 x cols 80wn..+79
    const unsigned short* w2l = (const unsigned short*)bufc;
    bf16x8 a2f[4];
    #pragma unroll
    for (int mt = 0; mt < 4; ++mt)
      a2f[mt] = lds8(&h1t[(wm * 64 + mt * 16 + rl) * 36 + g * 8]);
    #pragma unroll
    for (int jn = 0; jn < 5; ++jn) {
      bf16x8 bff = lds8(&w2l[g * 2400 + (wn * 80 + jn * 16 + rl) * 8]);
      #pragma unroll
      for (int mt = 0; mt < 4; ++mt)
        acc2[mt][jn] = MFMA(a2f[mt], bff, acc2[mt][jn]);
    }
    // epilogue after last k-tile of each q-net
    if (kt == 12) {
      __syncthreads();                // all h1t reads done; xred may alias-clobber
      const float* b2p = P.qp[qx * 6 + 3];
      const float* w3  = P.qp[qx * 6 + 4];
      const float* b3  = P.qp[qx * 6 + 5];
      float xp[4][4];
      #pragma unroll
      for (int mt = 0; mt < 4; ++mt)
        #pragma unroll
        for (int i = 0; i < 4; ++i) xp[mt][i] = 0.f;
      #pragma unroll
      for (int jn = 0; jn < 5; ++jn) {
        int n = wn * 80 + jn * 16 + rl;
        if (n < 300) {
          float bv = b2p[n], wv = w3[n];
          #pragma unroll
          for (int mt = 0; mt < 4; ++mt)
            #pragma unroll
            for (int i = 0; i < 4; ++i)
              xp[mt][i] += fmaxf(acc2[mt][jn][i] + bv, 0.f) * wv;
        }
      }
      #pragma unroll
      for (int off = 1; off < 16; off <<= 1)
        #pragma unroll
        for (int mt = 0; mt < 4; ++mt)
          #pragma unroll
          for (int i = 0; i < 4; ++i)
            xp[mt][i] += __shfl_xor(xp[mt][i], off, 64);
      if (rl == 0) {
        #pragma unroll
        for (int mt = 0; mt < 4; ++mt)
          #pragma unroll
          for (int i = 0; i < 4; ++i)
            xred[(wm * 64 + mt * 16 + g * 4 + i) * 4 + wn] = xp[mt][i];
      }
      __syncthreads();                // xred visible
      if (tid < TBROWS) {
        const float4 xv = *(const float4*)&xred[tid * 4];
        P.out[(size_t)qx * BTOT + (size_t)blockIdx.x * TBROWS + tid] =
            xv.x + xv.y + xv.z + xv.w + b3[0];
      }
    }
    // iter end: confirm tile tt+1 resident (counted wait: tile tt+2's 3 ops
    // may stay in flight; FIFO retirement => <=3 outstanding means tt+1 landed)
    if (tt < NTILE - 1) {
      if (tt == NTILE - 2) { asm volatile("s_waitcnt vmcnt(0)" ::: "memory"); }
      else                 { asm volatile("s_waitcnt vmcnt(3)" ::: "memory"); }
      __builtin_amdgcn_s_barrier();
    }
  }
}

extern "C" void kernel_launch(void* const* d_in, const int* in_sizes, int n_in,
                              void* d_out, int out_size, void* d_ws, size_t ws_size,
                              hipStream_t stream) {
  (void)in_sizes; (void)n_in; (void)out_size; (void)ws_size;
  PackP K;
  for (int i = 0; i < 12; ++i) K.qp[i] = (const float*)d_in[10 + i];
  K.ws = (unsigned short*)d_ws;
  pack_weights<<<dim3(178), dim3(512), 0, stream>>>(K);

  Params P;
  P.state  = (const float*)d_in[0];
  P.action = (const float*)d_in[1];
  P.f1w = (const float*)d_in[2]; P.f1b = (const float*)d_in[3];
  P.f2w = (const float*)d_in[4]; P.f2b = (const float*)d_in[5];
  P.f3w = (const float*)d_in[6]; P.f3b = (const float*)d_in[7];
  for (int i = 0; i < 12; ++i) P.qp[i] = (const float*)d_in[10 + i];
  P.img = (const unsigned char*)d_ws;
  P.out = (float*)d_out;
  critic_fused_kernel<<<dim3(NBLK), dim3(NTHR), 0, stream>>>(P);
}

// Round 6
// 141.926 us; speedup vs baseline: 1.6649x; 1.5746x over previous
//
#include <hip/hip_runtime.h>
#include <math.h>

// CriticGraphPolicy fused kernel, MI355X (gfx950). Round 6.
// Dead code removed: m_up=0, m_td=0, msg-MLP unused.
// R6: (a) phase-0 weights staged to LDS once per block (was: ~516 dependent
// global loads per thread -- the latency-bound constant across R1-R5);
// (b) 256 rows/block, 256 blocks = 1/CU, 48 MFMA per wave per k-iter
// (2x fatter barrier intervals); (c) no hazardous LDS aliasing: bufs/h1t/
// xumA/w0 disjoint (160,384 B), xred aliases only long-dead w0.
// K-loop DMA pipeline (3 bufs, depth-2 prefetch, counted vmcnt) kept from R5.

#define TBROWS 256
#define NTHR   512
#define BTOT   65536
#define NBLK   (BTOT / TBROWS)   // 256
#define TILE_B 23808             // packed weight tile: w2 19200 + w1 4608
#define TILE_U 11904
#define W2_B   19200
#define NTILE  26                // 2 q-nets x 13 k-tiles

// LDS byte offsets
#define OFF_H1T 71424            // h1t [256][36] u16 = 18432
#define OFF_XUM 89856            // xumA [256][72] u16 = 36864
#define OFF_W0  126720           // phase0 weights f32 [8416] = 33664; xred aliases
#define SMEM_SZ 160384

// w0 float indices
#define F1W 0
#define F1B 2112
#define F2W 2176
#define F2B 6272
#define F3W 6336
#define F3B 8384

typedef float  f32x4 __attribute__((ext_vector_type(4)));
typedef __bf16 bf16x8 __attribute__((ext_vector_type(8)));
typedef unsigned short u16x8 __attribute__((ext_vector_type(8)));

struct Params {
  const float* state; const float* action;
  const float* f1w; const float* f1b;
  const float* f2w; const float* f2b;
  const float* f3w; const float* f3b;
  const float* qp[12];          // q1: w1,b1,w2,b2,w3,b3 ; q2: same
  const unsigned char* img;     // packed bf16 weight images (d_ws)
  float* out;
};

struct PackP {
  const float* qp[12];
  unsigned short* ws;
};

__device__ __forceinline__ unsigned short f2b(float f) {
  union { float f; unsigned int u; } v; v.f = f;
  return (unsigned short)((v.u + 0x7fffu + ((v.u >> 16) & 1u)) >> 16);
}
__device__ __forceinline__ float b2f(unsigned short u) {
  union { unsigned int u; float f; } v; v.u = ((unsigned int)u) << 16;
  return v.f;
}
__device__ __forceinline__ f32x4 MFMA(bf16x8 a, bf16x8 b, f32x4 c) {
  return __builtin_amdgcn_mfma_f32_16x16x32_bf16(a, b, c, 0, 0, 0);
}
__device__ __forceinline__ bf16x8 lds8(const unsigned short* p) {
  return __builtin_bit_cast(bf16x8, *(const u16x8*)p);
}
__device__ __forceinline__ void gl_lds16(const void* g, void* l) {
  __builtin_amdgcn_global_load_lds(
      (__attribute__((address_space(1))) void*)(unsigned long long)(const char*)g,
      (__attribute__((address_space(3))) void*)(unsigned long long)(char*)l,
      16, 0, 0);
}
__device__ __forceinline__ void gl_lds4(const void* g, void* l) {
  __builtin_amdgcn_global_load_lds(
      (__attribute__((address_space(1))) void*)(unsigned long long)(const char*)g,
      (__attribute__((address_space(3))) void*)(unsigned long long)(char*)l,
      4, 0, 0);
}
__device__ __forceinline__ float ftanh(float x) {
  float e = __builtin_amdgcn_exp2f(x * 2.885390081777927f);
  return (e - 1.0f) * __builtin_amdgcn_rcpf(e + 1.0f);
}
__device__ __forceinline__ void cpy4(const float* g, float* l, int n4, int tid) {
  for (int i = tid; i < n4; i += NTHR)
    *(f32x4*)(l + 4 * i) = *(const f32x4*)(g + 4 * i);
}

// stage one 23808-B tile; exactly 3 vmem ops per wave (see R5).
__device__ __forceinline__ void stage_tile(const unsigned char* img, int tile,
                                           unsigned char* dst, int w, int lane) {
  const unsigned char* src = img + (size_t)tile * TILE_B;
  gl_lds16(src + (w << 10) + lane * 16,       dst + (w << 10));
  gl_lds16(src + ((8 + w) << 10) + lane * 16, dst + ((8 + w) << 10));
  if (w < 7)  gl_lds16(src + ((16 + w) << 10) + lane * 16, dst + ((16 + w) << 10));
  else        gl_lds4 (src + 23552 + lane * 4,             dst + 23552);
}

// ---------------- weight pack kernel (unchanged layout) ----------------
__global__ void pack_weights(PackP P) {
  const int b = blockIdx.x, tid = threadIdx.x;
  if (b < 61) {                       // w2: 26 tiles * 4 kc * 300 col
    int idx = b * 512 + tid;
    if (idx >= 31200) return;
    int col = idx % 300; int r = idx / 300;
    int kc = r & 3, tile = r >> 2;
    int q = tile / 13, kt = tile % 13;
    const float* w2 = P.qp[q * 6 + 2];
    unsigned short vals[8];
    #pragma unroll
    for (int koff = 0; koff < 8; ++koff) {
      int kg = kt * 32 + kc * 8 + koff;
      float v = (kg < 400) ? w2[kg * 300 + col] : 0.f;
      vals[koff] = f2b(v);
    }
    *(u16x8*)(P.ws + (size_t)tile * TILE_U + (size_t)(kc * 300 + col) * 8) = *(const u16x8*)vals;
  } else {                            // w1eff: 26 tiles * 2304 u16
    int idx = (b - 61) * 512 + tid;
    if (idx >= 59904) return;
    int e = idx % 2304, tile = idx / 2304;
    int q = tile / 13, kt = tile % 13;
    int col = e / 72, k = e % 72;
    int cg = kt * 32 + col;
    unsigned short v = 0;
    if (cg < 400) {
      if (k < 39) v = f2b(P.qp[q * 6 + 0][(6 + k) * 400 + cg]);
      else if (k == 39) v = f2b(P.qp[q * 6 + 1][cg]);
    }
    P.ws[(size_t)tile * TILE_U + 9600 + e] = v;
  }
}

// ---------------- main fused kernel ----------------
__global__ __launch_bounds__(NTHR, 2) void critic_fused_kernel(Params P) {
  __shared__ __align__(16) unsigned char smem[SMEM_SZ];
  unsigned char*  bufs = smem;
  unsigned short* h1t  = (unsigned short*)(smem + OFF_H1T);
  unsigned short* xumA = (unsigned short*)(smem + OFF_XUM);
  float*          w0   = (float*)(smem + OFF_W0);
  float*          xred = (float*)(smem + OFF_W0);   // w0 dead before first epilogue

  const int tid  = threadIdx.x;
  const int lane = tid & 63, w = tid >> 6;
  const int rl = lane & 15, g = lane >> 4;
  const int row = tid >> 1, sub = tid & 1;          // phase0: 2 threads per row
  const long grow = (long)blockIdx.x * TBROWS + row;

  // prefetch weight tiles 0,1 (disjoint from w0/xumA -- overlaps phase 0)
  stage_tile(P.img, 0, bufs, w, lane);
  stage_tile(P.img, 1, bufs + TILE_B, w, lane);

  // stage phase-0 weights into LDS (33,664 B)
  cpy4(P.f1w, w0 + F1W, 528, tid);
  cpy4(P.f1b, w0 + F1B, 16, tid);
  cpy4(P.f2w, w0 + F2W, 1024, tid);
  cpy4(P.f2b, w0 + F2B, 16, tid);
  cpy4(P.f3w, w0 + F3W, 512, tid);
  cpy4(P.f3b, w0 + F3B, 8, tid);
  __syncthreads();

  // ---------------- phase 0: feature MLP (f32 VALU, weights in LDS) --------
  float sa[33];
  {
    const float4* sp = (const float4*)(P.state + grow * 32);
    #pragma unroll
    for (int c = 0; c < 8; ++c) {
      float4 v = sp[c];
      sa[c*4+0] = v.x; sa[c*4+1] = v.y; sa[c*4+2] = v.z; sa[c*4+3] = v.w;
    }
    sa[32] = P.action[grow];
  }
  const int j0 = sub * 32;
  float acc[32];
  // fc1: h = tanh(l2norm(sa @ w1 + b1))
  #pragma unroll
  for (int j = 0; j < 32; ++j) acc[j] = w0[F1B + j0 + j];
  #pragma unroll 4
  for (int i = 0; i < 33; ++i) {
    const float s = sa[i];
    const f32x4* wr = (const f32x4*)&w0[F1W + i * 64 + j0];
    #pragma unroll
    for (int c = 0; c < 8; ++c) {
      f32x4 wv = wr[c];
      acc[c*4+0] += s * wv[0]; acc[c*4+1] += s * wv[1];
      acc[c*4+2] += s * wv[2]; acc[c*4+3] += s * wv[3];
    }
  }
  {
    float ss = 0.f;
    #pragma unroll
    for (int j = 0; j < 32; ++j) ss += acc[j] * acc[j];
    ss += __shfl_xor(ss, 1, 64);
    const float sc = 1.f / fmaxf(sqrtf(ss), 1e-12f);
    #pragma unroll
    for (int j = 0; j < 32; ++j) xumA[row * 72 + j0 + j] = f2b(ftanh(acc[j] * sc));
  }
  __syncthreads();
  // fc2: h2 = tanh(h @ w2[0:64] + b2)
  #pragma unroll
  for (int j = 0; j < 32; ++j) acc[j] = w0[F2B + j0 + j];
  #pragma unroll 4
  for (int i = 0; i < 64; ++i) {
    const float hv = b2f(xumA[row * 72 + i]);
    const f32x4* wr = (const f32x4*)&w0[F2W + i * 64 + j0];
    #pragma unroll
    for (int c = 0; c < 8; ++c) {
      f32x4 wv = wr[c];
      acc[c*4+0] += hv * wv[0]; acc[c*4+1] += hv * wv[1];
      acc[c*4+2] += hv * wv[2]; acc[c*4+3] += hv * wv[3];
    }
  }
  __syncthreads();
  #pragma unroll
  for (int j = 0; j < 32; ++j) xumA[row * 72 + j0 + j] = f2b(ftanh(acc[j]));
  __syncthreads();
  // fc3: msg_up = l2norm(h2 @ w3 + b3)
  const int j0m = sub * 16;
  float am[16];
  #pragma unroll
  for (int j = 0; j < 16; ++j) am[j] = w0[F3B + j0m + j];
  #pragma unroll 4
  for (int i = 0; i < 64; ++i) {
    const float hv = b2f(xumA[row * 72 + i]);
    const f32x4* wr = (const f32x4*)&w0[F3W + i * 32 + j0m];
    #pragma unroll
    for (int c = 0; c < 4; ++c) {
      f32x4 wv = wr[c];
      am[c*4+0] += hv * wv[0]; am[c*4+1] += hv * wv[1];
      am[c*4+2] += hv * wv[2]; am[c*4+3] += hv * wv[3];
    }
  }
  float sm = 0.f;
  #pragma unroll
  for (int j = 0; j < 16; ++j) sm += am[j] * am[j];
  sm += __shfl_xor(sm, 1, 64);
  const float scm = 1.f / fmaxf(sqrtf(sm), 1e-12f);
  __syncthreads();                    // h2 reads done; rebuild rows as xum
  // xum features (K pad 64): f0..2=pos, f3..5=pos, f6..37=msg, f38=act, f39=1
  #pragma unroll
  for (int k = 0; k < 12; ++k) xumA[row * 72 + 40 + sub * 12 + k] = 0;
  if (sub == 0) {
    #pragma unroll
    for (int c = 0; c < 3; ++c) {
      unsigned short pb = f2b(sa[c]);
      xumA[row * 72 + c] = pb;
      xumA[row * 72 + 3 + c] = pb;
    }
  } else {
    xumA[row * 72 + 38] = f2b(sa[32]);
    xumA[row * 72 + 39] = 0x3f80;     // 1.0
  }
  #pragma unroll
  for (int j = 0; j < 16; ++j) xumA[row * 72 + 6 + j0m + j] = f2b(am[j] * scm);
  __syncthreads();

  // layer1 A-fragments: wave w owns rows w*32 .. w*32+31 (two 16-row groups)
  bf16x8 af[2][2];
  #pragma unroll
  for (int hg = 0; hg < 2; ++hg) {
    af[hg][0] = lds8(&xumA[(w * 32 + hg * 16 + rl) * 72 + g * 8]);
    af[hg][1] = lds8(&xumA[(w * 32 + hg * 16 + rl) * 72 + 32 + g * 8]);
  }
  asm volatile("s_waitcnt vmcnt(0) lgkmcnt(0)" ::: "memory");
  __builtin_amdgcn_s_barrier();       // frags held; tiles 0,1 resident

  const int wm = w >> 2, wn = w & 3;  // layer2: 2 x 128-row halves, 4 x 80-col quarters
  f32x4 acc2[8][5];

  for (int tt = 0; tt < NTILE; ++tt) {
    const int kt = (tt < 13) ? tt : tt - 13;
    const int qx = (tt < 13) ? 0 : 1;
    unsigned char* bufc = bufs + (tt % 3) * TILE_B;
    if (kt == 0) {
      #pragma unroll
      for (int mt = 0; mt < 8; ++mt)
        #pragma unroll
        for (int jn = 0; jn < 5; ++jn) acc2[mt][jn] = (f32x4){0.f, 0.f, 0.f, 0.f};
    }
    if (tt + 2 < NTILE)
      stage_tile(P.img, tt + 2, bufs + ((tt + 2) % 3) * TILE_B, w, lane);

    // layer1: wave w -> its 32 rows x 32 cols (this tile's k-slice)
    const unsigned short* w1c = (const unsigned short*)(bufc + W2_B);
    #pragma unroll
    for (int hg = 0; hg < 2; ++hg) {
      #pragma unroll
      for (int nt = 0; nt < 2; ++nt) {
        f32x4 a1 = (f32x4){0.f, 0.f, 0.f, 0.f};
        a1 = MFMA(af[hg][0], lds8(&w1c[(nt * 16 + rl) * 72 + g * 8]), a1);
        a1 = MFMA(af[hg][1], lds8(&w1c[(nt * 16 + rl) * 72 + 32 + g * 8]), a1);
        #pragma unroll
        for (int i = 0; i < 4; ++i)
          h1t[(w * 32 + hg * 16 + g * 4 + i) * 36 + nt * 16 + rl] =
              f2b(fmaxf(a1[i], 0.f));
      }
    }
    asm volatile("s_waitcnt lgkmcnt(0)" ::: "memory");
    __builtin_amdgcn_s_barrier();     // h1t ready; prefetch DMAs stay in flight

    // layer2: wave (wm,wn): rows wm*128..+127 x cols wn*80..+79
    const unsigned short* w2l = (const unsigned short*)bufc;
    bf16x8 bff[5];
    #pragma unroll
    for (int jn = 0; jn < 5; ++jn)
      bff[jn] = lds8(&w2l[g * 2400 + (wn * 80 + jn * 16 + rl) * 8]);
    #pragma unroll
    for (int mt = 0; mt < 8; ++mt) {
      bf16x8 a2f = lds8(&h1t[(wm * 128 + mt * 16 + rl) * 36 + g * 8]);
      #pragma unroll
      for (int jn = 0; jn < 5; ++jn)
        acc2[mt][jn] = MFMA(a2f, bff[jn], acc2[mt][jn]);
    }

    // epilogue after last k-tile of each q-net
    if (kt == 12) {
      const float* b2p = P.qp[qx * 6 + 3];
      const float* w3  = P.qp[qx * 6 + 4];
      const float* b3  = P.qp[qx * 6 + 5];
      float xp[8][4];
      #pragma unroll
      for (int mt = 0; mt < 8; ++mt)
        #pragma unroll
        for (int i = 0; i < 4; ++i) xp[mt][i] = 0.f;
      #pragma unroll
      for (int jn = 0; jn < 5; ++jn) {
        int n = wn * 80 + jn * 16 + rl;
        if (n < 300) {
          float bv = b2p[n], wv = w3[n];
          #pragma unroll
          for (int mt = 0; mt < 8; ++mt)
            #pragma unroll
            for (int i = 0; i < 4; ++i)
              xp[mt][i] += fmaxf(acc2[mt][jn][i] + bv, 0.f) * wv;
        }
      }
      #pragma unroll
      for (int off = 1; off < 16; off <<= 1)
        #pragma unroll
        for (int mt = 0; mt < 8; ++mt)
          #pragma unroll
          for (int i = 0; i < 4; ++i)
            xp[mt][i] += __shfl_xor(xp[mt][i], off, 64);
      if (rl == 0) {
        #pragma unroll
        for (int mt = 0; mt < 8; ++mt)
          #pragma unroll
          for (int i = 0; i < 4; ++i)
            xred[(wm * 128 + mt * 16 + g * 4 + i) * 4 + wn] = xp[mt][i];
      }
      __syncthreads();                // xred visible (also drains prefetch; 2/26 iters)
      if (tid < TBROWS) {
        const float4 xv = *(const float4*)&xred[tid * 4];
        P.out[(size_t)qx * BTOT + (size_t)blockIdx.x * TBROWS + tid] =
            xv.x + xv.y + xv.z + xv.w + b3[0];
      }
    }
    // iter end: confirm tile tt+1 resident; tile tt+2 may stay in flight
    if (tt < NTILE - 1) {
      if (tt == NTILE - 2) { asm volatile("s_waitcnt vmcnt(0)" ::: "memory"); }
      else                 { asm volatile("s_waitcnt vmcnt(3)" ::: "memory"); }
      __builtin_amdgcn_s_barrier();
    }
  }
}

extern "C" void kernel_launch(void* const* d_in, const int* in_sizes, int n_in,
                              void* d_out, int out_size, void* d_ws, size_t ws_size,
                              hipStream_t stream) {
  (void)in_sizes; (void)n_in; (void)out_size; (void)ws_size;
  PackP K;
  for (int i = 0; i < 12; ++i) K.qp[i] = (const float*)d_in[10 + i];
  K.ws = (unsigned short*)d_ws;
  pack_weights<<<dim3(178), dim3(512), 0, stream>>>(K);

  Params P;
  P.state  = (const float*)d_in[0];
  P.action = (const float*)d_in[1];
  P.f1w = (const float*)d_in[2]; P.f1b = (const float*)d_in[3];
  P.f2w = (const float*)d_in[4]; P.f2b = (const float*)d_in[5];
  P.f3w = (const float*)d_in[6]; P.f3b = (const float*)d_in[7];
  for (int i = 0; i < 12; ++i) P.qp[i] = (const float*)d_in[10 + i];
  P.img = (const unsigned char*)d_ws;
  P.out = (float*)d_out;
  critic_fused_kernel<<<dim3(NBLK), dim3(NTHR), 0, stream>>>(P);
}